// Round 1
// baseline (625.677 us; speedup 1.0000x reference)
//
#include <hip/hip_runtime.h>

// Exphormer attention, fp32.
// Inputs: x[N,64], edge_attr[EG,64], edge_index[2,EG], Wq,bq,Wk,bk,We,be,Wv,bv
// Output: out[N,64] = segment_sum over dst of V[src]*exp(clip(score,-5,5))
// score[e,h] = sum_d K[src,h,d]*Q[dst,h,d]*(1/4)*Ee[e,h,d]

#define H_DIM 64

// ---------------- Kernel 1: fused Q/K/V projection ----------------
// block 256 = 4 waves; each wave does 4 nodes/iter; W^T staged in LDS padded
__global__ __launch_bounds__(256) void proj_kernel(
    const float* __restrict__ x,
    const float* __restrict__ Wq, const float* __restrict__ bq,
    const float* __restrict__ Wk, const float* __restrict__ bk,
    const float* __restrict__ Wv, const float* __restrict__ bv,
    float* __restrict__ Q, float* __restrict__ K, float* __restrict__ V,
    int n)
{
    __shared__ float WqT[64 * 65];
    __shared__ float WkT[64 * 65];
    __shared__ float WvT[64 * 65];
    __shared__ float xs[4][4][64];

    const int tid  = threadIdx.x;
    const int wave = tid >> 6;
    const int lane = tid & 63;

    // stage transposed weights: WT[i*65 + j] = W[j*64 + i]
    // write bank = (i*65+j)%32 = (i+j)%32 -> conflict-free across a wave
    #pragma unroll
    for (int k = 0; k < 16; ++k) {
        int idx = tid + k * 256;
        int j = idx >> 6, i = idx & 63;
        WqT[i * 65 + j] = Wq[idx];
        WkT[i * 65 + j] = Wk[idx];
        WvT[i * 65 + j] = Wv[idx];
    }
    const float bqv = bq[lane];
    const float bkv = bk[lane];
    const float bvv = bv[lane];
    __syncthreads();

    for (int blockbase = blockIdx.x * 16; blockbase < n;
         blockbase += gridDim.x * 16) {
        int base = blockbase + wave * 4;
        // stage 4 x-rows for this wave
        #pragma unroll
        for (int j = 0; j < 4; ++j) {
            int node = base + j;
            xs[wave][j][lane] = (node < n) ? x[node * 64 + lane] : 0.f;
        }
        __syncthreads();

        float accq[4], acck[4], accv[4];
        #pragma unroll
        for (int j = 0; j < 4; ++j) { accq[j] = bqv; acck[j] = bkv; accv[j] = bvv; }

        #pragma unroll
        for (int f = 0; f < 16; ++f) {
            float wq[4], wk[4], wv[4];
            #pragma unroll
            for (int u = 0; u < 4; ++u) {
                int i = 4 * f + u;
                wq[u] = WqT[i * 65 + lane];   // bank (i+lane)%32 -> 2-way, free
                wk[u] = WkT[i * 65 + lane];
                wv[u] = WvT[i * 65 + lane];
            }
            #pragma unroll
            for (int j = 0; j < 4; ++j) {
                float4 xv = *reinterpret_cast<const float4*>(&xs[wave][j][4 * f]);
                accq[j] = fmaf(xv.x, wq[0], accq[j]);
                accq[j] = fmaf(xv.y, wq[1], accq[j]);
                accq[j] = fmaf(xv.z, wq[2], accq[j]);
                accq[j] = fmaf(xv.w, wq[3], accq[j]);
                acck[j] = fmaf(xv.x, wk[0], acck[j]);
                acck[j] = fmaf(xv.y, wk[1], acck[j]);
                acck[j] = fmaf(xv.z, wk[2], acck[j]);
                acck[j] = fmaf(xv.w, wk[3], acck[j]);
                accv[j] = fmaf(xv.x, wv[0], accv[j]);
                accv[j] = fmaf(xv.y, wv[1], accv[j]);
                accv[j] = fmaf(xv.z, wv[2], accv[j]);
                accv[j] = fmaf(xv.w, wv[3], accv[j]);
            }
        }

        #pragma unroll
        for (int j = 0; j < 4; ++j) {
            int node = base + j;
            if (node < n) {
                Q[node * 64 + lane] = accq[j];
                K[node * 64 + lane] = acck[j];
                V[node * 64 + lane] = accv[j];
            }
        }
        __syncthreads();   // protect xs before next iteration
    }
}

// ---------------- Kernel 2: per-edge attention + scatter ----------------
// block 256 = 4 waves; 1 wave = 1 edge; lane = output dim (head = lane>>4)
// We row `lane` kept in 64 VGPRs; edge_attr row staged in LDS, read as
// uniform-address (broadcast) float4 -> conflict-free.
__global__ __launch_bounds__(256) void edge_kernel(
    const float* __restrict__ ea, const int* __restrict__ ei,
    const float* __restrict__ Q, const float* __restrict__ K,
    const float* __restrict__ V,
    const float* __restrict__ We, const float* __restrict__ be,
    float* __restrict__ out, int EG)
{
    __shared__ float ea_s[4][64];

    const int tid  = threadIdx.x;
    const int wave = tid >> 6;
    const int lane = tid & 63;

    // We row for this lane -> 16 float4 in registers (16 KB matrix, L2-hot)
    float4 w[16];
    const float4* wrow = reinterpret_cast<const float4*>(We + lane * 64);
    #pragma unroll
    for (int f = 0; f < 16; ++f) w[f] = wrow[f];
    const float bias = be[lane];

    for (int blockbase = blockIdx.x * 4; blockbase < EG;
         blockbase += gridDim.x * 4) {
        const int e = blockbase + wave;
        const bool act = (e < EG);
        int src = 0, dst = 0;
        float eav = 0.f;
        if (act) {
            src = ei[e];
            dst = ei[EG + e];
            eav = ea[e * 64 + lane];
        }
        ea_s[wave][lane] = eav;
        __syncthreads();

        if (act) {
            // Ee[lane] = be[lane] + sum_i ea[i] * We[lane,i]
            float acc = bias;
            const float4* eas4 = reinterpret_cast<const float4*>(ea_s[wave]);
            #pragma unroll
            for (int f = 0; f < 16; ++f) {
                float4 xv = eas4[f];           // uniform addr -> LDS broadcast
                acc = fmaf(xv.x, w[f].x, acc);
                acc = fmaf(xv.y, w[f].y, acc);
                acc = fmaf(xv.z, w[f].z, acc);
                acc = fmaf(xv.w, w[f].w, acc);
            }
            // per-lane partial score, reduce over the 16-lane head group
            float kv = K[src * 64 + lane];
            float qv = Q[dst * 64 + lane];
            float t  = kv * qv * 0.25f * acc;
            t += __shfl_xor(t, 1);
            t += __shfl_xor(t, 2);
            t += __shfl_xor(t, 4);
            t += __shfl_xor(t, 8);
            t = fminf(fmaxf(t, -5.f), 5.f);
            float s = __expf(t);
            float m = V[src * 64 + lane] * s;
            atomicAdd(&out[dst * 64 + lane], m);
        }
        __syncthreads();   // ea_s reuse
    }
}

extern "C" void kernel_launch(void* const* d_in, const int* in_sizes, int n_in,
                              void* d_out, int out_size, void* d_ws, size_t ws_size,
                              hipStream_t stream) {
    const float* x   = (const float*)d_in[0];
    const float* ea  = (const float*)d_in[1];
    const int*   ei  = (const int*)d_in[2];
    const float* Wq  = (const float*)d_in[3];
    const float* bq  = (const float*)d_in[4];
    const float* Wk  = (const float*)d_in[5];
    const float* bk  = (const float*)d_in[6];
    const float* We  = (const float*)d_in[7];
    const float* be  = (const float*)d_in[8];
    const float* Wv  = (const float*)d_in[9];
    const float* bv  = (const float*)d_in[10];
    float* out = (float*)d_out;

    const int n  = in_sizes[0] / 64;   // 50000
    const int EG = in_sizes[1] / 64;   // 1600000

    float* Q = (float*)d_ws;
    float* K = Q + (size_t)n * 64;
    float* V = K + (size_t)n * 64;

    // output is accumulated via atomics -> must zero every call
    hipMemsetAsync(d_out, 0, (size_t)out_size * sizeof(float), stream);

    const int projGrid = (n + 15) / 16;
    proj_kernel<<<projGrid, 256, 0, stream>>>(x, Wq, bq, Wk, bk, Wv, bv,
                                              Q, K, V, n);

    const int edgeGrid = 4096;
    edge_kernel<<<edgeGrid, 256, 0, stream>>>(ea, ei, Q, K, V, We, be,
                                              out, EG);
}